// Round 3
// baseline (428.917 us; speedup 1.0000x reference)
//
#include <hip/hip_runtime.h>
#include <hip/hip_bf16.h>

#define AS1 __attribute__((address_space(1)))
#define AS3 __attribute__((address_space(3)))

typedef __attribute__((ext_vector_type(8))) short bfrag8;   // 8 bf16 in 4 VGPRs
typedef __attribute__((ext_vector_type(4))) float floatx4;  // MFMA accumulator

static constexpr int M = 4096, N = 4096, K = 4096;
static constexpr long long NELEM = 16777216LL;   // 4096*4096 (both x and W)
static constexpr int PB = 1024;                  // prep blocks

// ---------- round-to-nearest-even fp32 -> bf16 ----------
__device__ __forceinline__ unsigned short f2bf(float f) {
    unsigned int u = __float_as_uint(f);
    u += 0x7FFFu + ((u >> 16) & 1u);
    return (unsigned short)(u >> 16);
}

// ---------- ternary quantize: bf16 {-1,0,+1}; exact fp32 division as reference ----------
__device__ __forceinline__ unsigned short tq(float v, float scale_f) {
    float wn = v / scale_f;
    if (fabsf(wn) > 0.5f)
        return (unsigned short)(0x3F80u | ((__float_as_uint(v) >> 16) & 0x8000u));
    return 0;
}

// ---------- dual block reduce (double), broadcast result to ALL threads ----------
__device__ __forceinline__ void block_reduce2_bcast(double& a, double& b) {
    #pragma unroll
    for (int off = 32; off > 0; off >>= 1) {
        a += __shfl_down(a, off, 64);
        b += __shfl_down(b, off, 64);
    }
    __shared__ double pa[4], pb[4];
    int lane = threadIdx.x & 63, wv = threadIdx.x >> 6;
    if (lane == 0) { pa[wv] = a; pb[wv] = b; }
    __syncthreads();
    a = pa[0] + pa[1] + pa[2] + pa[3];
    b = pb[0] + pb[1] + pb[2] + pb[3];
}

// ---------- R8: single fused prep kernel with device-scope grid barrier ----------
// R2 structure: prep_reduce(2048 blk) -> quantize_w(1024 blk) = 3 serial dispatches,
// ~168us total minus gemm. Fuse into ONE kernel: phase A streams x (reduce+convert)
// and w (reduce) with the SAME per-block spans and SAME single-chain f64 order as R2
// -> partials bit-identical. Grid barrier (all 1024 blocks co-resident by
// __launch_bounds__(256,4): 4 blk/CU x 256 CU = 1024; counter memset to 0 per launch).
// Fold partials with R2's exact tree -> scales bit-identical; phase B re-reads w
// (L3-hot, 64MB << 256MB) and quantizes with identical tq -> output bit-identical.
__global__ __launch_bounds__(256, 4) void prep_coop(
        const float* __restrict__ x, unsigned short* __restrict__ xb,
        const float* __restrict__ w, unsigned short* __restrict__ qb,
        double* __restrict__ px, double* __restrict__ pw,
        float* __restrict__ scales, unsigned int* __restrict__ bc) {
    const int t = threadIdx.x;
    const int b = blockIdx.x;
    const long long base = (long long)b * 4096 + t;   // float4 index

    // ---- phase A1: stream x: reduce |x| + bf16 convert + store (R2 order) ----
    const float4* x4 = (const float4*)x;
    ushort4* xb4 = (ushort4*)xb;
    double sx = 0.0;
    #pragma unroll
    for (int i = 0; i < 16; i++) {
        float4 v = x4[base + i * 256];
        sx += (double)fabsf(v.x); sx += (double)fabsf(v.y);
        sx += (double)fabsf(v.z); sx += (double)fabsf(v.w);
        ushort4 r;
        r.x = f2bf(v.x); r.y = f2bf(v.y);
        r.z = f2bf(v.z); r.w = f2bf(v.w);
        xb4[base + i * 256] = r;
    }

    // ---- phase A2: stream w: reduce |w| (R2 order) ----
    const float4* w4 = (const float4*)w;
    double sw = 0.0;
    #pragma unroll
    for (int i = 0; i < 16; i++) {
        float4 v = w4[base + i * 256];
        sw += (double)fabsf(v.x); sw += (double)fabsf(v.y);
        sw += (double)fabsf(v.z); sw += (double)fabsf(v.w);
    }

    block_reduce2_bcast(sx, sw);   // same add tree as R2's block_reduce
    if (t == 0) { px[b] = sx; pw[b] = sw; }

    // ---- device-scope grid barrier (bc memset to 0 before this kernel) ----
    if (t == 0) {
        __threadfence();                         // release partials
        atomicAdd(bc, 1u);
        while (atomicAdd(bc, 0u) < (unsigned)gridDim.x)
            __builtin_amdgcn_s_sleep(2);
        __threadfence();                         // acquire partials
    }
    __syncthreads();

    // ---- fold partials: exactly R2's quantize_w tree ----
    double fx = 0.0, fw = 0.0;
    #pragma unroll
    for (int i = 0; i < 4; i++) { fx += px[t + i * 256]; fw += pw[t + i * 256]; }
    block_reduce2_bcast(fx, fw);
    const float scale_w = (float)fmax(fw / (double)NELEM, 1e-8);
    const float scale_x = (float)fmax(fx / (double)NELEM, 1e-8);
    if (b == 0 && t == 0) { scales[0] = scale_w; scales[1] = scale_x; }

    // ---- phase B: quantize w from L3-hot re-read (identical to R2 quantize_w) ----
    ushort4* q4 = (ushort4*)qb;
    float4 vv[16];
    #pragma unroll
    for (int i = 0; i < 16; i++) vv[i] = w4[base + i * 256];
    #pragma unroll
    for (int i = 0; i < 16; i++) {
        ushort4 r;
        r.x = tq(vv[i].x, scale_w); r.y = tq(vv[i].y, scale_w);
        r.z = tq(vv[i].z, scale_w); r.w = tq(vv[i].w, scale_w);
        q4[base + i * 256] = r;
    }
}

// ---------- R7 GEMM: 256x256 / BK=64 / 8-wave, counted-vmcnt pipeline (UNCHANGED) ----------
// P1(t): A(t+1).h0 -> other buf; P2(t): A(t+1).h1; P3(t): B(t+2).h0 -> same buf;
// P4(t): B(t+2).h1; s_waitcnt vmcnt(4) after MFMA. Never vmcnt(0) in loop.
// XOR-chunk LDS swizzle; bank conflicts = 0 verified. 119.5us / 1150 TF / MfmaUtil 50%.
__global__ __launch_bounds__(512, 2) void gemm_bt256(
        const unsigned short* __restrict__ A,
        const unsigned short* __restrict__ B,
        const float* __restrict__ bias,
        const float* __restrict__ scales,   // [0]=wscale, [1]=iscale
        float* __restrict__ out) {
    __shared__ alignas(16) char lds[131072];

    const int tid = threadIdx.x;
    const int lane = tid & 63;
    const int wv = tid >> 6;            // 0..7
    const int wm = wv & 1;              // 2 M-waves (128 rows each)
    const int wn = wv >> 1;             // 4 N-waves (64 cols each)
    const int col16 = lane & 15;
    const int quad  = lane >> 4;

    const int bid = blockIdx.x;
    const int swz = (bid & 7) * 32 + (bid >> 3);
    const int bx = swz & 15;            // n-tile
    const int by = swz >> 4;            // m-tile
    const int m0 = by * 256;
    const int n0 = bx * 256;

    const int srow8  = lane >> 3;            // row within 8-row group
    const int schunk = (lane & 7) ^ srow8;   // k-chunk this lane fetches
    const int scol   = schunk * 8;           // element offset

    floatx4 acc[8][4];
    #pragma unroll
    for (int i = 0; i < 8; i++)
        #pragma unroll
        for (int j = 0; j < 4; j++)
            acc[i][j] = (floatx4)0.0f;

    char* buf0 = (char*)lds;
    char* buf1 = (char*)lds + 65536;

    auto stage_half = [&](const unsigned short* __restrict__ gmat, int base0,
                          char* region, long long k0, int h) {
        #pragma unroll
        for (int l = 0; l < 2; ++l) {
            const int c = wv * 2 + l;                       // 0..15 within half
            const unsigned short* g = gmat
                + (size_t)(base0 + h * 128 + c * 8 + srow8) * (size_t)K
                + (size_t)k0 + scol;
            char* d = region + h * 16384 + c * 1024 + lane * 16;
            __builtin_amdgcn_global_load_lds((const AS1 void*)g, (AS3 void*)d, 16, 0, 0);
        }
    };

    // prologue: tile0 (4 halves) + B(1) (2 halves); keep 4 newest in flight
    stage_half(B, n0, buf0 + 32768, 0, 0);
    stage_half(B, n0, buf0 + 32768, 0, 1);
    stage_half(A, m0, buf0,         0, 0);
    stage_half(A, m0, buf0,         0, 1);
    stage_half(B, n0, buf1 + 32768, 64, 0);
    stage_half(B, n0, buf1 + 32768, 64, 1);
    asm volatile("s_waitcnt vmcnt(4)" ::: "memory");
    __builtin_amdgcn_s_barrier();

    auto tile_body = [&](char* bufc, char* bufn, int t) {
        const bool stA = (t + 1) < 64;
        const bool stB = (t + 2) < 64;
        const long long kA = (long long)(t + 1) * 64;
        const long long kB = (long long)(t + 2) * 64;
        const char* bA = bufc;
        const char* bB = bufc + 32768;

        bfrag8 bf[4][2];
        #pragma unroll
        for (int j = 0; j < 4; ++j) {
            const int rB = wn * 64 + j * 16 + col16;
            #pragma unroll
            for (int kk = 0; kk < 2; ++kk)
                bf[j][kk] = *(const bfrag8*)(bB + rB * 128 +
                                (((kk * 4 + quad) ^ (col16 & 7)) << 4));
        }

        #pragma unroll
        for (int q = 0; q < 4; ++q) {
            bfrag8 af[2][2];
            #pragma unroll
            for (int di = 0; di < 2; ++di) {
                const int rA = wm * 128 + (q * 2 + di) * 16 + col16;
                #pragma unroll
                for (int kk = 0; kk < 2; ++kk)
                    af[di][kk] = *(const bfrag8*)(bA + rA * 128 +
                                    (((kk * 4 + quad) ^ (col16 & 7)) << 4));
            }
            if (q == 0 && stA) stage_half(A, m0, bufn, kA, 0);
            if (q == 1 && stA) stage_half(A, m0, bufn, kA, 1);
            if (q == 2 && stB) stage_half(B, n0, bufc + 32768, kB, 0);
            if (q == 3 && stB) stage_half(B, n0, bufc + 32768, kB, 1);

            __builtin_amdgcn_s_barrier();
            asm volatile("s_waitcnt lgkmcnt(0)" ::: "memory");
            __builtin_amdgcn_s_setprio(1);
            #pragma unroll
            for (int di = 0; di < 2; ++di)
                #pragma unroll
                for (int j = 0; j < 4; ++j) {
                    acc[q * 2 + di][j] = __builtin_amdgcn_mfma_f32_16x16x32_bf16(
                        af[di][0], bf[j][0], acc[q * 2 + di][j], 0, 0, 0);
                    acc[q * 2 + di][j] = __builtin_amdgcn_mfma_f32_16x16x32_bf16(
                        af[di][1], bf[j][1], acc[q * 2 + di][j], 0, 0, 0);
                }
            __builtin_amdgcn_s_setprio(0);
            if (q == 3) asm volatile("s_waitcnt vmcnt(4)" ::: "memory");
            __builtin_amdgcn_s_barrier();
        }
    };

    for (int t2 = 0; t2 < 32; ++t2) {
        tile_body(buf0, buf1, 2 * t2);
        tile_body(buf1, buf0, 2 * t2 + 1);
    }

    const float wscale = scales[0];
    const float iscale = scales[1];

    float bv[4];
    #pragma unroll
    for (int j = 0; j < 4; ++j)
        bv[j] = bias[n0 + wn * 64 + j * 16 + col16] * iscale;

    #pragma unroll
    for (int i = 0; i < 8; ++i) {
        const int mbase = m0 + wm * 128 + i * 16 + quad * 4;
        #pragma unroll
        for (int j = 0; j < 4; ++j) {
            const int n = n0 + wn * 64 + j * 16 + col16;
            #pragma unroll
            for (int r = 0; r < 4; ++r)
                out[(size_t)(mbase + r) * N + n] = acc[i][j][r] * wscale + bv[j];
        }
    }
}

extern "C" void kernel_launch(void* const* d_in, const int* in_sizes, int n_in,
                              void* d_out, int out_size, void* d_ws, size_t ws_size,
                              hipStream_t stream) {
    const float* x    = (const float*)d_in[0];   // (2,2048,4096) fp32
    const float* w    = (const float*)d_in[1];   // (4096,4096) fp32
    const float* bias = (const float*)d_in[2];   // (4096,) fp32
    float* out = (float*)d_out;                  // (2,2048,4096) fp32

    char* ws = (char*)d_ws;
    float*  scales = (float*)ws;                       // 16 B
    unsigned int* bc = (unsigned int*)(ws + 64);       // grid-barrier counter
    double* px     = (double*)(ws + 256);              // 1024 doubles (8 KB)
    double* pw     = (double*)(ws + 256 + PB * 8);     // 1024 doubles (8 KB)
    unsigned short* xb = (unsigned short*)(ws + 16640);                      // 32 MB bf16 x
    unsigned short* qb = (unsigned short*)(ws + 16640 + (size_t)NELEM * 2);  // 32 MB bf16 qW

    hipMemsetAsync(bc, 0, sizeof(unsigned int), stream);
    prep_coop<<<PB, 256, 0, stream>>>(x, xb, w, qb, px, pw, scales, bc);
    gemm_bt256<<<dim3(256), 512, 0, stream>>>(xb, qb, bias, scales, out);
}

// Round 4
// 317.927 us; speedup vs baseline: 1.3491x; 1.3491x over previous
//
#include <hip/hip_runtime.h>
#include <hip/hip_bf16.h>

#define AS1 __attribute__((address_space(1)))
#define AS3 __attribute__((address_space(3)))

typedef __attribute__((ext_vector_type(8))) short bfrag8;   // 8 bf16 in 4 VGPRs
typedef __attribute__((ext_vector_type(4))) float floatx4;  // MFMA accumulator

static constexpr int M = 4096, N = 4096, K = 4096;
static constexpr long long NELEM = 16777216LL;   // 4096*4096 (both x and W)
static constexpr int PB = 1024;                  // prep blocks per array

// ---------- round-to-nearest-even fp32 -> bf16 ----------
__device__ __forceinline__ unsigned short f2bf(float f) {
    unsigned int u = __float_as_uint(f);
    u += 0x7FFFu + ((u >> 16) & 1u);
    return (unsigned short)(u >> 16);
}

// ---------- ternary quantize: bf16 {-1,0,+1}; exact fp32 division as reference ----------
__device__ __forceinline__ unsigned short tq(float v, float scale_f) {
    float wn = v / scale_f;
    if (fabsf(wn) > 0.5f)
        return (unsigned short)(0x3F80u | ((__float_as_uint(v) >> 16) & 0x8000u));
    return 0;
}

// ---------- block reduce (double) -> value on thread 0 ----------
__device__ __forceinline__ double block_reduce(double s) {
    #pragma unroll
    for (int off = 32; off > 0; off >>= 1) s += __shfl_down(s, off, 64);
    __shared__ double part[4];
    int lane = threadIdx.x & 63, wv = threadIdx.x >> 6;
    if (lane == 0) part[wv] = s;
    __syncthreads();
    return part[0] + part[1] + part[2] + part[3];
}

// ---------- dual block reduce (double), broadcast result to ALL threads ----------
__device__ __forceinline__ void block_reduce2_bcast(double& a, double& b) {
    #pragma unroll
    for (int off = 32; off > 0; off >>= 1) {
        a += __shfl_down(a, off, 64);
        b += __shfl_down(b, off, 64);
    }
    __shared__ double pa[4], pb[4];
    int lane = threadIdx.x & 63, wv = threadIdx.x >> 6;
    if (lane == 0) { pa[wv] = a; pb[wv] = b; }
    __syncthreads();
    a = pa[0] + pa[1] + pa[2] + pa[3];
    b = pb[0] + pb[1] + pb[2] + pb[3];
}

// ---------- prep (R2-proven): blocks [0,PB) -> sum|x| + x->bf16 ; [PB,2PB) -> sum|w| ----------
__global__ __launch_bounds__(256) void prep_reduce(
        const float* __restrict__ x, unsigned short* __restrict__ xb,
        const float* __restrict__ w,
        double* __restrict__ px, double* __restrict__ pw) {
    const int b = blockIdx.x;
    const bool isW = b >= PB;
    const int rb = isW ? b - PB : b;
    const float4* src = (const float4*)(isW ? w : x);
    const long long base = (long long)rb * 4096 + threadIdx.x;  // float4 index

    float4 v[16];
    #pragma unroll
    for (int i = 0; i < 16; i++) v[i] = src[base + i * 256];    // 16 independent loads

    double s = 0.0;
    #pragma unroll
    for (int i = 0; i < 16; i++) {
        s += (double)fabsf(v[i].x); s += (double)fabsf(v[i].y);
        s += (double)fabsf(v[i].z); s += (double)fabsf(v[i].w);
    }

    if (!isW) {
        ushort4* xb4 = (ushort4*)xb;
        #pragma unroll
        for (int i = 0; i < 16; i++) {
            ushort4 r;
            r.x = f2bf(v[i].x); r.y = f2bf(v[i].y);
            r.z = f2bf(v[i].z); r.w = f2bf(v[i].w);
            xb4[base + i * 256] = r;
        }
    }

    double bs = block_reduce(s);
    if (threadIdx.x == 0) (isW ? pw : px)[rb] = bs;
}

// ---------- quantize w (R2-proven) + inline scale finalize ----------
__global__ __launch_bounds__(256) void quantize_w(
        const float* __restrict__ w, unsigned short* __restrict__ qb,
        const double* __restrict__ px, const double* __restrict__ pw,
        float* __restrict__ scales) {
    const int t = threadIdx.x;
    double sx = 0.0, sw = 0.0;
    #pragma unroll
    for (int i = 0; i < 4; i++) { sx += px[t + i * 256]; sw += pw[t + i * 256]; }
    block_reduce2_bcast(sx, sw);
    const float scale_w = (float)fmax(sw / (double)NELEM, 1e-8);
    const float scale_x = (float)fmax(sx / (double)NELEM, 1e-8);
    if (blockIdx.x == 0 && t == 0) { scales[0] = scale_w; scales[1] = scale_x; }

    const float4* w4 = (const float4*)w;
    ushort4* q4 = (ushort4*)qb;
    const long long base = (long long)blockIdx.x * 4096 + t;
    float4 v[16];
    #pragma unroll
    for (int i = 0; i < 16; i++) v[i] = w4[base + i * 256];
    #pragma unroll
    for (int i = 0; i < 16; i++) {
        ushort4 r;
        r.x = tq(v[i].x, scale_w); r.y = tq(v[i].y, scale_w);
        r.z = tq(v[i].z, scale_w); r.w = tq(v[i].w, scale_w);
        q4[base + i * 256] = r;
    }
}

// ---------- R9 GEMM: deep counted-vmcnt pipeline (front-loaded reads, t+2 staging) ----------
// Key change vs R7: fragment reads are FRONT-LOADED so LDS regions free mid-tile:
//   q0: read bf[0..3] (8) + af[0..1] (4); MFMA rows 0,1        (B region fully read here)
//   q1: read af[2..3] (4); stage B(t+2).h0; MFMA rows 2,3
//   q2: read af[0..3]gen2 (8); stage B(t+2).h1; MFMA rows 4,5  (A region fully read here)
//   q3: stage A(t+2).h0+h1 (4 loads); MFMA rows 6,7; vmcnt(8)
// Tile t stages tile t+2 into the SAME buffer (regions provably read-complete: every
// phase's lgkmcnt(0) precedes its closing barrier, and stages issue after that barrier).
// vmcnt(8) retires tile t+1's loads (issued 5-7 phases earlier) keeping t+2's 8 in
// flight -> never drains, full HBM-latency cover (m201/T4 discipline).
// Per-acc-element MFMA order identical to R7 -> bitwise-same output.
__global__ __launch_bounds__(512, 2) void gemm_bt256(
        const unsigned short* __restrict__ A,
        const unsigned short* __restrict__ B,
        const float* __restrict__ bias,
        const float* __restrict__ scales,   // [0]=wscale, [1]=iscale
        float* __restrict__ out) {
    __shared__ alignas(16) char lds[131072];

    const int tid = threadIdx.x;
    const int lane = tid & 63;
    const int wv = tid >> 6;            // 0..7
    const int wm = wv & 1;              // 2 M-waves (128 rows each)
    const int wn = wv >> 1;             // 4 N-waves (64 cols each)
    const int col16 = lane & 15;
    const int quad  = lane >> 4;

    const int bid = blockIdx.x;
    const int swz = (bid & 7) * 32 + (bid >> 3);
    const int bx = swz & 15;            // n-tile
    const int by = swz >> 4;            // m-tile
    const int m0 = by * 256;
    const int n0 = bx * 256;

    const int srow8  = lane >> 3;            // row within 8-row group
    const int schunk = (lane & 7) ^ srow8;   // k-chunk this lane fetches
    const int scol   = schunk * 8;           // element offset

    floatx4 acc[8][4];
    #pragma unroll
    for (int i = 0; i < 8; i++)
        #pragma unroll
        for (int j = 0; j < 4; j++)
            acc[i][j] = (floatx4)0.0f;

    char* buf0 = (char*)lds;
    char* buf1 = (char*)lds + 65536;

    // stage one half-tile (128 rows x 64 k): 2 global_load_lds per thread
    auto stage_half = [&](const unsigned short* __restrict__ gmat, int base0,
                          char* region, long long k0, int h) {
        #pragma unroll
        for (int l = 0; l < 2; ++l) {
            const int c = wv * 2 + l;                       // 0..15 within half
            const unsigned short* g = gmat
                + (size_t)(base0 + h * 128 + c * 8 + srow8) * (size_t)K
                + (size_t)k0 + scol;
            char* d = region + h * 16384 + c * 1024 + lane * 16;
            __builtin_amdgcn_global_load_lds((const AS1 void*)g, (AS3 void*)d, 16, 0, 0);
        }
    };

    #define LGKM0   asm volatile("s_waitcnt lgkmcnt(0)" ::: "memory")
    #define BARRIER __builtin_amdgcn_s_barrier()

    // MFMA one row-pair (rows rbase,rbase+1) from fa0/fa1 x all bf
    #define MFMA_PAIR(rbase, fa0, fa1)                                                 \
        __builtin_amdgcn_s_setprio(1);                                                 \
        _Pragma("unroll")                                                              \
        for (int j = 0; j < 4; ++j) {                                                  \
            acc[(rbase)][j] = __builtin_amdgcn_mfma_f32_16x16x32_bf16(                 \
                (fa0)[0], bf[j][0], acc[(rbase)][j], 0, 0, 0);                         \
            acc[(rbase)][j] = __builtin_amdgcn_mfma_f32_16x16x32_bf16(                 \
                (fa0)[1], bf[j][1], acc[(rbase)][j], 0, 0, 0);                         \
            acc[(rbase)+1][j] = __builtin_amdgcn_mfma_f32_16x16x32_bf16(               \
                (fa1)[0], bf[j][0], acc[(rbase)+1][j], 0, 0, 0);                       \
            acc[(rbase)+1][j] = __builtin_amdgcn_mfma_f32_16x16x32_bf16(               \
                (fa1)[1], bf[j][1], acc[(rbase)+1][j], 0, 0, 0);                       \
        }                                                                              \
        __builtin_amdgcn_s_setprio(0)

    // ---- prologue: stage T0 and T1 fully (16 loads); retire T0, keep T1 in flight ----
    stage_half(B, n0, buf0 + 32768, 0, 0);
    stage_half(B, n0, buf0 + 32768, 0, 1);
    stage_half(A, m0, buf0,         0, 0);
    stage_half(A, m0, buf0,         0, 1);
    stage_half(B, n0, buf1 + 32768, 64, 0);
    stage_half(B, n0, buf1 + 32768, 64, 1);
    stage_half(A, m0, buf1,         64, 0);
    stage_half(A, m0, buf1,         64, 1);
    asm volatile("s_waitcnt vmcnt(8)" ::: "memory");
    BARRIER;

    auto tile_body = [&](char* bufc, int t) {
        const bool st = (t + 2) < 64;
        const long long kN = (long long)(t + 2) * 64;
        const char* bA = bufc;
        const char* bB = bufc + 32768;
        bfrag8 bf[4][2], af[4][2];

        // ---------- phase 0: bf all (8 reads) + af rows 0,1 (4 reads); MFMA rows 0,1 ----
        #pragma unroll
        for (int j = 0; j < 4; ++j) {
            const int rB = wn * 64 + j * 16 + col16;
            #pragma unroll
            for (int kk = 0; kk < 2; ++kk)
                bf[j][kk] = *(const bfrag8*)(bB + rB * 128 +
                                (((kk * 4 + quad) ^ (col16 & 7)) << 4));
        }
        #pragma unroll
        for (int r = 0; r < 2; ++r) {
            const int rA = wm * 128 + r * 16 + col16;
            #pragma unroll
            for (int kk = 0; kk < 2; ++kk)
                af[r][kk] = *(const bfrag8*)(bA + rA * 128 +
                                (((kk * 4 + quad) ^ (col16 & 7)) << 4));
        }
        BARRIER; LGKM0;
        MFMA_PAIR(0, af[0], af[1]);
        BARRIER;

        // ---------- phase 1: af rows 2,3 (4 reads); stage B(t+2).h0; MFMA rows 2,3 ----
        #pragma unroll
        for (int r = 2; r < 4; ++r) {
            const int rA = wm * 128 + r * 16 + col16;
            #pragma unroll
            for (int kk = 0; kk < 2; ++kk)
                af[r][kk] = *(const bfrag8*)(bA + rA * 128 +
                                (((kk * 4 + quad) ^ (col16 & 7)) << 4));
        }
        if (st) stage_half(B, n0, bufc + 32768, kN, 0);
        BARRIER; LGKM0;
        MFMA_PAIR(2, af[2], af[3]);
        BARRIER;

        // ---------- phase 2: af gen2 rows 4..7 (8 reads); stage B(t+2).h1; MFMA rows 4,5
        #pragma unroll
        for (int r = 0; r < 4; ++r) {
            const int rA = wm * 128 + (4 + r) * 16 + col16;
            #pragma unroll
            for (int kk = 0; kk < 2; ++kk)
                af[r][kk] = *(const bfrag8*)(bA + rA * 128 +
                                (((kk * 4 + quad) ^ (col16 & 7)) << 4));
        }
        if (st) stage_half(B, n0, bufc + 32768, kN, 1);
        BARRIER; LGKM0;
        MFMA_PAIR(4, af[0], af[1]);
        BARRIER;

        // ---------- phase 3: stage A(t+2).h0+h1; MFMA rows 6,7; counted vmcnt ----------
        if (st) {
            stage_half(A, m0, bufc, kN, 0);
            stage_half(A, m0, bufc, kN, 1);
        }
        BARRIER; LGKM0;
        MFMA_PAIR(6, af[2], af[3]);
        if (t < 62)       asm volatile("s_waitcnt vmcnt(8)" ::: "memory");
        else if (t == 62) asm volatile("s_waitcnt vmcnt(0)" ::: "memory");
        BARRIER;
    };

    for (int t2 = 0; t2 < 32; ++t2) {
        tile_body(buf0, 2 * t2);
        tile_body(buf1, 2 * t2 + 1);
    }

    // ---- epilogue ----
    const float wscale = scales[0];
    const float iscale = scales[1];

    float bv[4];
    #pragma unroll
    for (int j = 0; j < 4; ++j)
        bv[j] = bias[n0 + wn * 64 + j * 16 + col16] * iscale;

    #pragma unroll
    for (int i = 0; i < 8; ++i) {
        const int mbase = m0 + wm * 128 + i * 16 + quad * 4;
        #pragma unroll
        for (int j = 0; j < 4; ++j) {
            const int n = n0 + wn * 64 + j * 16 + col16;
            #pragma unroll
            for (int r = 0; r < 4; ++r)
                out[(size_t)(mbase + r) * N + n] = acc[i][j][r] * wscale + bv[j];
        }
    }
    #undef MFMA_PAIR
    #undef LGKM0
    #undef BARRIER
}

extern "C" void kernel_launch(void* const* d_in, const int* in_sizes, int n_in,
                              void* d_out, int out_size, void* d_ws, size_t ws_size,
                              hipStream_t stream) {
    const float* x    = (const float*)d_in[0];   // (2,2048,4096) fp32
    const float* w    = (const float*)d_in[1];   // (4096,4096) fp32
    const float* bias = (const float*)d_in[2];   // (4096,) fp32
    float* out = (float*)d_out;                  // (2,2048,4096) fp32

    char* ws = (char*)d_ws;
    float*  scales = (float*)ws;                       // 16 B
    double* px     = (double*)(ws + 256);              // 1024 doubles (8 KB)
    double* pw     = (double*)(ws + 256 + PB * 8);     // 1024 doubles (8 KB)
    unsigned short* xb = (unsigned short*)(ws + 16640);                      // 32 MB bf16 x
    unsigned short* qb = (unsigned short*)(ws + 16640 + (size_t)NELEM * 2);  // 32 MB bf16 qW

    prep_reduce<<<2 * PB, 256, 0, stream>>>(x, xb, w, px, pw);
    quantize_w<<<PB, 256, 0, stream>>>(w, qb, px, pw, scales);

    gemm_bt256<<<dim3(256), 512, 0, stream>>>(xb, qb, bias, scales, out);
}

// Round 5
// 294.442 us; speedup vs baseline: 1.4567x; 1.0798x over previous
//
#include <hip/hip_runtime.h>
#include <hip/hip_bf16.h>

#define AS1 __attribute__((address_space(1)))
#define AS3 __attribute__((address_space(3)))

typedef __attribute__((ext_vector_type(8))) short bfrag8;   // 8 bf16 in 4 VGPRs
typedef __attribute__((ext_vector_type(4))) float floatx4;  // MFMA accumulator

static constexpr int M = 4096, N = 4096, K = 4096;
static constexpr long long NELEM = 16777216LL;   // 4096*4096 (both x and W)
static constexpr int PB = 1024;                  // prep blocks per array

// ---------- round-to-nearest-even fp32 -> bf16 ----------
__device__ __forceinline__ unsigned short f2bf(float f) {
    unsigned int u = __float_as_uint(f);
    u += 0x7FFFu + ((u >> 16) & 1u);
    return (unsigned short)(u >> 16);
}

// ---------- ternary quantize: bf16 {-1,0,+1}; exact fp32 division as reference ----------
__device__ __forceinline__ unsigned short tq(float v, float scale_f) {
    float wn = v / scale_f;
    if (fabsf(wn) > 0.5f)
        return (unsigned short)(0x3F80u | ((__float_as_uint(v) >> 16) & 0x8000u));
    return 0;
}

// ---------- block reduce (double) -> value on thread 0 ----------
__device__ __forceinline__ double block_reduce(double s) {
    #pragma unroll
    for (int off = 32; off > 0; off >>= 1) s += __shfl_down(s, off, 64);
    __shared__ double part[4];
    int lane = threadIdx.x & 63, wv = threadIdx.x >> 6;
    if (lane == 0) part[wv] = s;
    __syncthreads();
    return part[0] + part[1] + part[2] + part[3];
}

// ---------- dual block reduce (double), broadcast result to ALL threads ----------
__device__ __forceinline__ void block_reduce2_bcast(double& a, double& b) {
    #pragma unroll
    for (int off = 32; off > 0; off >>= 1) {
        a += __shfl_down(a, off, 64);
        b += __shfl_down(b, off, 64);
    }
    __shared__ double pa[4], pb[4];
    int lane = threadIdx.x & 63, wv = threadIdx.x >> 6;
    if (lane == 0) { pa[wv] = a; pb[wv] = b; }
    __syncthreads();
    a = pa[0] + pa[1] + pa[2] + pa[3];
    b = pb[0] + pb[1] + pb[2] + pb[3];
}

// ---------- prep (R2-proven): blocks [0,PB) -> sum|x| + x->bf16 ; [PB,2PB) -> sum|w| ----------
__global__ __launch_bounds__(256) void prep_reduce(
        const float* __restrict__ x, unsigned short* __restrict__ xb,
        const float* __restrict__ w,
        double* __restrict__ px, double* __restrict__ pw) {
    const int b = blockIdx.x;
    const bool isW = b >= PB;
    const int rb = isW ? b - PB : b;
    const float4* src = (const float4*)(isW ? w : x);
    const long long base = (long long)rb * 4096 + threadIdx.x;  // float4 index

    float4 v[16];
    #pragma unroll
    for (int i = 0; i < 16; i++) v[i] = src[base + i * 256];    // 16 independent loads

    double s = 0.0;
    #pragma unroll
    for (int i = 0; i < 16; i++) {
        s += (double)fabsf(v[i].x); s += (double)fabsf(v[i].y);
        s += (double)fabsf(v[i].z); s += (double)fabsf(v[i].w);
    }

    if (!isW) {
        ushort4* xb4 = (ushort4*)xb;
        #pragma unroll
        for (int i = 0; i < 16; i++) {
            ushort4 r;
            r.x = f2bf(v[i].x); r.y = f2bf(v[i].y);
            r.z = f2bf(v[i].z); r.w = f2bf(v[i].w);
            xb4[base + i * 256] = r;
        }
    }

    double bs = block_reduce(s);
    if (threadIdx.x == 0) (isW ? pw : px)[rb] = bs;
}

// ---------- quantize w (R2-proven) + inline scale finalize ----------
__global__ __launch_bounds__(256) void quantize_w(
        const float* __restrict__ w, unsigned short* __restrict__ qb,
        const double* __restrict__ px, const double* __restrict__ pw,
        float* __restrict__ scales) {
    const int t = threadIdx.x;
    double sx = 0.0, sw = 0.0;
    #pragma unroll
    for (int i = 0; i < 4; i++) { sx += px[t + i * 256]; sw += pw[t + i * 256]; }
    block_reduce2_bcast(sx, sw);
    const float scale_w = (float)fmax(sw / (double)NELEM, 1e-8);
    const float scale_x = (float)fmax(sx / (double)NELEM, 1e-8);
    if (blockIdx.x == 0 && t == 0) { scales[0] = scale_w; scales[1] = scale_x; }

    const float4* w4 = (const float4*)w;
    ushort4* q4 = (ushort4*)qb;
    const long long base = (long long)blockIdx.x * 4096 + t;
    float4 v[16];
    #pragma unroll
    for (int i = 0; i < 16; i++) v[i] = w4[base + i * 256];
    #pragma unroll
    for (int i = 0; i < 16; i++) {
        ushort4 r;
        r.x = tq(v[i].x, scale_w); r.y = tq(v[i].y, scale_w);
        r.z = tq(v[i].z, scale_w); r.w = tq(v[i].w, scale_w);
        q4[base + i * 256] = r;
    }
}

// ---------- R10 GEMM: R7 schedule + uniform-cover stage remap ----------
// R7 (proven 119.5us/1150TF/MfmaUtil 50%): stage slots A.h0@q0 A.h1@q1 B.h0@q2 B.h1@q3,
// vmcnt(4)@q3 -> min cover (A.h1) only ~2.5 phases. R9's deep rework regressed (uneven
// phases). R10 keeps R7's skeleton EXACTLY, only remapping stage slots for uniform cover:
//   pre-q0: A(t+1).h0 -> bufn  (region last read t-1 q3, lgkm0'd before final barrier)
//   q0: A(t+1).h1 -> bufn ; q1: B(t+2).h0 -> bufc.B ; q2: B(t+2).h1 ; q3: none
//   q3: MFMA -> vmcnt(4) (12 outstanding -> retires B(t+1)+A(t+1), keeps B(t+2)) -> barrier
// Cover: A 3.5-4 phases (was 2.5-3.5), B 5.5-6.5. Early lgkmcnt(8) hint before q0 barrier
// (12 ds_reads pending; m201 recipe). Per-element MFMA order identical -> bitwise output.
__global__ __launch_bounds__(512, 2) void gemm_bt256(
        const unsigned short* __restrict__ A,
        const unsigned short* __restrict__ B,
        const float* __restrict__ bias,
        const float* __restrict__ scales,   // [0]=wscale, [1]=iscale
        float* __restrict__ out) {
    __shared__ alignas(16) char lds[131072];

    const int tid = threadIdx.x;
    const int lane = tid & 63;
    const int wv = tid >> 6;            // 0..7
    const int wm = wv & 1;              // 2 M-waves (128 rows each)
    const int wn = wv >> 1;             // 4 N-waves (64 cols each)
    const int col16 = lane & 15;
    const int quad  = lane >> 4;

    const int bid = blockIdx.x;
    const int swz = (bid & 7) * 32 + (bid >> 3);
    const int bx = swz & 15;            // n-tile
    const int by = swz >> 4;            // m-tile
    const int m0 = by * 256;
    const int n0 = bx * 256;

    const int srow8  = lane >> 3;            // row within 8-row group
    const int schunk = (lane & 7) ^ srow8;   // k-chunk this lane fetches
    const int scol   = schunk * 8;           // element offset

    floatx4 acc[8][4];
    #pragma unroll
    for (int i = 0; i < 8; i++)
        #pragma unroll
        for (int j = 0; j < 4; j++)
            acc[i][j] = (floatx4)0.0f;

    char* buf0 = (char*)lds;
    char* buf1 = (char*)lds + 65536;

    // stage one half-tile (128 rows x 64 k): 2 global_load_lds per thread
    auto stage_half = [&](const unsigned short* __restrict__ gmat, int base0,
                          char* region, long long k0, int h) {
        #pragma unroll
        for (int l = 0; l < 2; ++l) {
            const int c = wv * 2 + l;                       // 0..15 within half
            const unsigned short* g = gmat
                + (size_t)(base0 + h * 128 + c * 8 + srow8) * (size_t)K
                + (size_t)k0 + scol;
            char* d = region + h * 16384 + c * 1024 + lane * 16;
            __builtin_amdgcn_global_load_lds((const AS1 void*)g, (AS3 void*)d, 16, 0, 0);
        }
    };

    // ---- prologue: tile0 (4 halves) + B(1) (2 halves); keep B(1) 4 in flight ----
    stage_half(B, n0, buf0 + 32768, 0, 0);
    stage_half(B, n0, buf0 + 32768, 0, 1);
    stage_half(A, m0, buf0,         0, 0);
    stage_half(A, m0, buf0,         0, 1);
    stage_half(B, n0, buf1 + 32768, 64, 0);
    stage_half(B, n0, buf1 + 32768, 64, 1);
    asm volatile("s_waitcnt vmcnt(4)" ::: "memory");
    __builtin_amdgcn_s_barrier();

    auto tile_body = [&](char* bufc, char* bufn, int t) {
        const bool stA = (t + 1) < 64;
        const bool stB = (t + 2) < 64;
        const long long kA = (long long)(t + 1) * 64;
        const long long kB = (long long)(t + 2) * 64;
        const char* bA = bufc;
        const char* bB = bufc + 32768;

        // pre-q0: A(t+1).h0 into the other buffer (earliest safe slot)
        if (stA) stage_half(A, m0, bufn, kA, 0);

        // B fragments for the whole tile (8 x ds_read_b128), held in regs
        bfrag8 bf[4][2];
        #pragma unroll
        for (int j = 0; j < 4; ++j) {
            const int rB = wn * 64 + j * 16 + col16;
            #pragma unroll
            for (int kk = 0; kk < 2; ++kk)
                bf[j][kk] = *(const bfrag8*)(bB + rB * 128 +
                                (((kk * 4 + quad) ^ (col16 & 7)) << 4));
        }

        #pragma unroll
        for (int q = 0; q < 4; ++q) {
            bfrag8 af[2][2];
            #pragma unroll
            for (int di = 0; di < 2; ++di) {
                const int rA = wm * 128 + (q * 2 + di) * 16 + col16;
                #pragma unroll
                for (int kk = 0; kk < 2; ++kk)
                    af[di][kk] = *(const bfrag8*)(bA + rA * 128 +
                                    (((kk * 4 + quad) ^ (col16 & 7)) << 4));
            }
            // uniform-cover staging slots
            if (q == 0 && stA) stage_half(A, m0, bufn, kA, 1);
            if (q == 1 && stB) stage_half(B, n0, bufc + 32768, kB, 0);
            if (q == 2 && stB) stage_half(B, n0, bufc + 32768, kB, 1);

            if (q == 0) asm volatile("s_waitcnt lgkmcnt(8)" ::: "memory");  // early drain hint
            __builtin_amdgcn_s_barrier();
            asm volatile("s_waitcnt lgkmcnt(0)" ::: "memory");
            __builtin_amdgcn_s_setprio(1);
            #pragma unroll
            for (int di = 0; di < 2; ++di)
                #pragma unroll
                for (int j = 0; j < 4; ++j) {
                    acc[q * 2 + di][j] = __builtin_amdgcn_mfma_f32_16x16x32_bf16(
                        af[di][0], bf[j][0], acc[q * 2 + di][j], 0, 0, 0);
                    acc[q * 2 + di][j] = __builtin_amdgcn_mfma_f32_16x16x32_bf16(
                        af[di][1], bf[j][1], acc[q * 2 + di][j], 0, 0, 0);
                }
            __builtin_amdgcn_s_setprio(0);
            if (q == 3) {
                if (t < 62)       asm volatile("s_waitcnt vmcnt(4)" ::: "memory");
                else if (t == 62) asm volatile("s_waitcnt vmcnt(0)" ::: "memory");
            }
            __builtin_amdgcn_s_barrier();
        }
    };

    for (int t2 = 0; t2 < 32; ++t2) {
        tile_body(buf0, buf1, 2 * t2);
        tile_body(buf1, buf0, 2 * t2 + 1);
    }

    // ---- epilogue ----
    const float wscale = scales[0];
    const float iscale = scales[1];

    float bv[4];
    #pragma unroll
    for (int j = 0; j < 4; ++j)
        bv[j] = bias[n0 + wn * 64 + j * 16 + col16] * iscale;

    #pragma unroll
    for (int i = 0; i < 8; ++i) {
        const int mbase = m0 + wm * 128 + i * 16 + quad * 4;
        #pragma unroll
        for (int j = 0; j < 4; ++j) {
            const int n = n0 + wn * 64 + j * 16 + col16;
            #pragma unroll
            for (int r = 0; r < 4; ++r)
                out[(size_t)(mbase + r) * N + n] = acc[i][j][r] * wscale + bv[j];
        }
    }
}

extern "C" void kernel_launch(void* const* d_in, const int* in_sizes, int n_in,
                              void* d_out, int out_size, void* d_ws, size_t ws_size,
                              hipStream_t stream) {
    const float* x    = (const float*)d_in[0];   // (2,2048,4096) fp32
    const float* w    = (const float*)d_in[1];   // (4096,4096) fp32
    const float* bias = (const float*)d_in[2];   // (4096,) fp32
    float* out = (float*)d_out;                  // (2,2048,4096) fp32

    char* ws = (char*)d_ws;
    float*  scales = (float*)ws;                       // 16 B
    double* px     = (double*)(ws + 256);              // 1024 doubles (8 KB)
    double* pw     = (double*)(ws + 256 + PB * 8);     // 1024 doubles (8 KB)
    unsigned short* xb = (unsigned short*)(ws + 16640);                      // 32 MB bf16 x
    unsigned short* qb = (unsigned short*)(ws + 16640 + (size_t)NELEM * 2);  // 32 MB bf16 qW

    prep_reduce<<<2 * PB, 256, 0, stream>>>(x, xb, w, px, pw);
    quantize_w<<<PB, 256, 0, stream>>>(w, qb, px, pw, scales);

    gemm_bt256<<<dim3(256), 512, 0, stream>>>(xb, qb, bias, scales, out);
}